// Round 1
// baseline (583.981 us; speedup 1.0000x reference)
//
#include <hip/hip_runtime.h>
#include <math.h>

#define B_   8
#define M_   4096
#define N_   4096
#define DM   1024
#define DC   768
#define DH   16
#define CHUNKS 32
#define ROWS_PER_CHUNK (N_/CHUNKS)   // 128

__device__ __forceinline__ float elu1(float t) {
    // jax.nn.elu(t) + 1:  t>0 ? t+1 : exp(t)
    return t > 0.0f ? t + 1.0f : expf(t);
}

// ---------------------------------------------------------------------------
// Kernel A: K = elu1(context @ Wk + bk), V = context @ Wv + bv
// block = 256 threads, 64 rows/block, 4 threads per row (each owns 4 head dims)
// grid = B_*N_/64 = 512
// ---------------------------------------------------------------------------
__global__ __launch_bounds__(256) void kv_kernel(
    const float* __restrict__ ctx,
    const float* __restrict__ Wk, const float* __restrict__ bk,
    const float* __restrict__ Wv, const float* __restrict__ bv,
    float* __restrict__ Kbuf, float* __restrict__ Vbuf)
{
    const int t = threadIdx.x;
    const int q = t & 3;          // which 4-dim slice of the 16 head dims
    const int r = t >> 2;         // row within block
    const size_t row = (size_t)blockIdx.x * 64 + r;   // global row in [0, B*N)
    const float* crow = ctx + row * DC;

    float ak0=0.f, ak1=0.f, ak2=0.f, ak3=0.f;
    float av0=0.f, av1=0.f, av2=0.f, av3=0.f;

    #pragma unroll 4
    for (int i = 0; i < DC; i += 4) {
        const float4 c = *reinterpret_cast<const float4*>(crow + i);
        const float cv[4] = {c.x, c.y, c.z, c.w};
        #pragma unroll
        for (int ii = 0; ii < 4; ++ii) {
            const float cc = cv[ii];
            const float4 wk = *reinterpret_cast<const float4*>(Wk + (size_t)(i+ii)*DH + q*4);
            const float4 wv = *reinterpret_cast<const float4*>(Wv + (size_t)(i+ii)*DH + q*4);
            ak0 += cc*wk.x; ak1 += cc*wk.y; ak2 += cc*wk.z; ak3 += cc*wk.w;
            av0 += cc*wv.x; av1 += cc*wv.y; av2 += cc*wv.z; av3 += cc*wv.w;
        }
    }

    const float4 bkv = *reinterpret_cast<const float4*>(bk + q*4);
    const float4 bvv = *reinterpret_cast<const float4*>(bv + q*4);

    float4 kout, vout;
    kout.x = elu1(ak0 + bkv.x); kout.y = elu1(ak1 + bkv.y);
    kout.z = elu1(ak2 + bkv.z); kout.w = elu1(ak3 + bkv.w);
    vout.x = av0 + bvv.x; vout.y = av1 + bvv.y;
    vout.z = av2 + bvv.z; vout.w = av3 + bvv.w;

    *reinterpret_cast<float4*>(Kbuf + row*DH + q*4) = kout;
    *reinterpret_cast<float4*>(Vbuf + row*DH + q*4) = vout;
}

// ---------------------------------------------------------------------------
// Kernel B1: partial KtV (16x16) + Ksum (16) per (batch, chunk of 128 rows)
// grid = B_*CHUNKS = 256 blocks, block = 256 threads
// part layout: [B][CHUNKS][272]  (256 KtV + 16 Ksum)
// ---------------------------------------------------------------------------
__global__ __launch_bounds__(256) void reduce1(
    const float* __restrict__ Kbuf, const float* __restrict__ Vbuf,
    float* __restrict__ part)
{
    const int b  = blockIdx.x / CHUNKS;
    const int ch = blockIdx.x % CHUNKS;
    const size_t base = ((size_t)b * N_ + (size_t)ch * ROWS_PER_CHUNK) * DH;

    __shared__ float sk[ROWS_PER_CHUNK][DH];
    __shared__ float sv[ROWS_PER_CHUNK][DH];

    const int t = threadIdx.x;
    // load 128*16 = 2048 floats each; 256 threads * 2 iters * float4
    for (int idx = t*4; idx < ROWS_PER_CHUNK*DH; idx += 256*4) {
        *reinterpret_cast<float4*>(&sk[0][0] + idx) =
            *reinterpret_cast<const float4*>(Kbuf + base + idx);
        *reinterpret_cast<float4*>(&sv[0][0] + idx) =
            *reinterpret_cast<const float4*>(Vbuf + base + idx);
    }
    __syncthreads();

    const int d = t >> 4, e = t & 15;
    float acc = 0.f;
    #pragma unroll 8
    for (int n = 0; n < ROWS_PER_CHUNK; ++n) acc += sk[n][d] * sv[n][e];
    float* p = part + ((size_t)b*CHUNKS + ch) * 272;
    p[t] = acc;

    if (t < DH) {
        float s = 0.f;
        #pragma unroll 8
        for (int n = 0; n < ROWS_PER_CHUNK; ++n) s += sk[n][t];
        p[256 + t] = s;
    }
}

// ---------------------------------------------------------------------------
// Kernel B2: combine CHUNKS partials -> final KtV[b][256], Ksum[b][16]
// grid = B_, block = 320 (272 active)
// ---------------------------------------------------------------------------
__global__ __launch_bounds__(320) void reduce2(
    const float* __restrict__ part,
    float* __restrict__ ktv, float* __restrict__ ksum)
{
    const int b = blockIdx.x;
    const int t = threadIdx.x;
    if (t < 272) {
        float s = 0.f;
        #pragma unroll
        for (int ch = 0; ch < CHUNKS; ++ch)
            s += part[((size_t)b*CHUNKS + ch) * 272 + t];
        if (t < 256) ktv[(size_t)b*256 + t] = s;
        else         ksum[(size_t)b*DH + (t - 256)] = s;
    }
}

// ---------------------------------------------------------------------------
// Kernel C: Q = elu1(x @ Wq + bq); num = Q@KtV; den = Q.Ksum + 1e-6;
//           out = (num/den) @ Wo + bo
// block = 256 threads, 64 rows/block, 4 threads per row; grid = B_*M_/64 = 512
// ---------------------------------------------------------------------------
__global__ __launch_bounds__(256) void out_kernel(
    const float* __restrict__ x,
    const float* __restrict__ Wq, const float* __restrict__ bq,
    const float* __restrict__ ktv, const float* __restrict__ ksum,
    const float* __restrict__ Wo, const float* __restrict__ bo,
    float* __restrict__ out)
{
    const int t = threadIdx.x;
    const int q = t & 3;
    const int r = t >> 2;
    const size_t row = (size_t)blockIdx.x * 64 + r;   // in [0, B*M)
    const int b = (int)(row >> 12);                   // 4096 rows per batch
    const float* xrow = x + row * DM;

    // ---- Q: this lane owns head dims [4q, 4q+4) ----
    float a0=0.f, a1=0.f, a2=0.f, a3=0.f;
    #pragma unroll 4
    for (int i = 0; i < DM; i += 4) {
        const float4 c = *reinterpret_cast<const float4*>(xrow + i);
        const float cv[4] = {c.x, c.y, c.z, c.w};
        #pragma unroll
        for (int ii = 0; ii < 4; ++ii) {
            const float cc = cv[ii];
            const float4 wq = *reinterpret_cast<const float4*>(Wq + (size_t)(i+ii)*DH + q*4);
            a0 += cc*wq.x; a1 += cc*wq.y; a2 += cc*wq.z; a3 += cc*wq.w;
        }
    }
    const float4 bqv = *reinterpret_cast<const float4*>(bq + q*4);
    float qv[4];
    qv[0] = elu1(a0 + bqv.x); qv[1] = elu1(a1 + bqv.y);
    qv[2] = elu1(a2 + bqv.z); qv[3] = elu1(a3 + bqv.w);

    // ---- gather all 16 q values across the quad ----
    float qall[16];
    #pragma unroll
    for (int s = 0; s < 4; ++s) {
        #pragma unroll
        for (int j = 0; j < 4; ++j)
            qall[s*4 + j] = __shfl(qv[j], s, 4);
    }

    // ---- num (this lane's 4 output dims) and den ----
    const float* KT = ktv + (size_t)b*256;
    const float* KS = ksum + (size_t)b*DH;
    float n0=0.f, n1=0.f, n2=0.f, n3=0.f;
    float den = 1e-6f;
    #pragma unroll
    for (int d = 0; d < DH; ++d) {
        const float4 kt = *reinterpret_cast<const float4*>(KT + d*DH + q*4);
        const float qd = qall[d];
        n0 += qd*kt.x; n1 += qd*kt.y; n2 += qd*kt.z; n3 += qd*kt.w;
        den += qd * KS[d];
    }
    const float inv = 1.0f / den;
    float o[4] = {n0*inv, n1*inv, n2*inv, n3*inv};

    // ---- gather all 16 o values across the quad ----
    float oall[16];
    #pragma unroll
    for (int s = 0; s < 4; ++s) {
        #pragma unroll
        for (int j = 0; j < 4; ++j)
            oall[s*4 + j] = __shfl(o[j], s, 4);
    }

    // ---- output projection: this lane covers cols [q*256, q*256+256) ----
    float* orow = out + row * DM + q*256;
    const float* bop = bo + q*256;
    const float* Wop = Wo + q*256;
    for (int j = 0; j < 256; j += 4) {
        float4 acc = *reinterpret_cast<const float4*>(bop + j);
        #pragma unroll
        for (int e = 0; e < DH; ++e) {
            const float4 w = *reinterpret_cast<const float4*>(Wop + (size_t)e*DM + j);
            const float oe = oall[e];
            acc.x += oe*w.x; acc.y += oe*w.y; acc.z += oe*w.z; acc.w += oe*w.w;
        }
        *reinterpret_cast<float4*>(orow + j) = acc;
    }
}

// ---------------------------------------------------------------------------
extern "C" void kernel_launch(void* const* d_in, const int* in_sizes, int n_in,
                              void* d_out, int out_size, void* d_ws, size_t ws_size,
                              hipStream_t stream) {
    const float* x    = (const float*)d_in[0];
    const float* ctx  = (const float*)d_in[1];
    const float* Wq   = (const float*)d_in[2];
    const float* bq   = (const float*)d_in[3];
    const float* Wk   = (const float*)d_in[4];
    const float* bk   = (const float*)d_in[5];
    const float* Wv   = (const float*)d_in[6];
    const float* bv   = (const float*)d_in[7];
    const float* Wo   = (const float*)d_in[8];
    const float* bo   = (const float*)d_in[9];
    float* out = (float*)d_out;

    // workspace layout (floats)
    float* ws = (float*)d_ws;
    float* Kbuf = ws;                               // B*N*16 = 524288
    float* Vbuf = Kbuf + (size_t)B_*N_*DH;          // 524288
    float* part = Vbuf + (size_t)B_*N_*DH;          // B*CHUNKS*272 = 69632
    float* ktv  = part + (size_t)B_*CHUNKS*272;     // B*256
    float* ksum = ktv  + (size_t)B_*256;            // B*16

    kv_kernel<<<dim3(B_*N_/64), dim3(256), 0, stream>>>(ctx, Wk, bk, Wv, bv, Kbuf, Vbuf);
    reduce1<<<dim3(B_*CHUNKS), dim3(256), 0, stream>>>(Kbuf, Vbuf, part);
    reduce2<<<dim3(B_), dim3(320), 0, stream>>>(part, ktv, ksum);
    out_kernel<<<dim3(B_*M_/64), dim3(256), 0, stream>>>(x, Wq, bq, ktv, ksum, Wo, bo, out);
}

// Round 2
// 397.422 us; speedup vs baseline: 1.4694x; 1.4694x over previous
//
#include <hip/hip_runtime.h>
#include <math.h>

#define B_   8
#define M_   4096
#define N_   4096
#define DM   1024
#define DC   768
#define DH   16
#define CHUNKS 64
#define RPC (N_/CHUNKS)   // 64 rows per chunk

__device__ __forceinline__ float elu1(float t) {
    return t > 0.0f ? t + 1.0f : expf(t);
}
__device__ __forceinline__ float4 ld4(const float* p) { return *reinterpret_cast<const float4*>(p); }
__device__ __forceinline__ void  st4(float* p, float4 v) { *reinterpret_cast<float4*>(p) = v; }
__device__ __forceinline__ float4 sx4(float4 v, int m) {
    float4 r;
    r.x = __shfl_xor(v.x, m); r.y = __shfl_xor(v.y, m);
    r.z = __shfl_xor(v.z, m); r.w = __shfl_xor(v.w, m);
    return r;
}
__device__ __forceinline__ float4 add4(float4 a, float4 b) {
    float4 r; r.x=a.x+b.x; r.y=a.y+b.y; r.z=a.z+b.z; r.w=a.w+b.w; return r;
}
__device__ __forceinline__ void fma4(float4& a, float s, float4 w) {
    a.x = fmaf(s, w.x, a.x); a.y = fmaf(s, w.y, a.y);
    a.z = fmaf(s, w.z, a.z); a.w = fmaf(s, w.w, a.w);
}

// ---------------------------------------------------------------------------
// Kernel A: K = elu1(ctx @ Wk + bk), V = ctx @ Wv + bv
// lane: q = t&3 (4 head dims), s = (t>>2)&3 (K-slice of 768 -> 192 each),
//       r = t>>4 (16 rows/block). grid = B*N/16 = 2048
// ---------------------------------------------------------------------------
__global__ __launch_bounds__(256) void kv_kernel(
    const float* __restrict__ ctx,
    const float* __restrict__ Wk, const float* __restrict__ bk,
    const float* __restrict__ Wv, const float* __restrict__ bv,
    float* __restrict__ Kbuf, float* __restrict__ Vbuf)
{
    const int t = threadIdx.x;
    const int q = t & 3;
    const int s = (t >> 2) & 3;
    const int r = t >> 4;
    const size_t row = (size_t)blockIdx.x * 16 + r;
    const float* crow = ctx + row * DC + s * (DC/4);

    float4 ka = {0,0,0,0}, va = {0,0,0,0};
    #pragma unroll 4
    for (int ii = 0; ii < DC/16; ++ii) {       // 48 float4 chunks
        const float4 c = ld4(crow + ii*4);
        const float cc[4] = {c.x, c.y, c.z, c.w};
        const int i0 = s*(DC/4) + ii*4;
        #pragma unroll
        for (int u = 0; u < 4; ++u) {
            const float4 wk = ld4(Wk + (size_t)(i0+u)*DH + q*4);
            const float4 wv = ld4(Wv + (size_t)(i0+u)*DH + q*4);
            fma4(ka, cc[u], wk);
            fma4(va, cc[u], wv);
        }
    }
    // combine the 4 K-slices (lanes differing in bits 2,3)
    ka = add4(ka, sx4(ka, 4)); ka = add4(ka, sx4(ka, 8));
    va = add4(va, sx4(va, 4)); va = add4(va, sx4(va, 8));

    if (s == 0) {
        const float4 bkv = ld4(bk + q*4);
        float4 ko;
        ko.x = elu1(ka.x + bkv.x); ko.y = elu1(ka.y + bkv.y);
        ko.z = elu1(ka.z + bkv.z); ko.w = elu1(ka.w + bkv.w);
        st4(Kbuf + row*DH + q*4, ko);
    } else if (s == 1) {
        const float4 bvv = ld4(bv + q*4);
        float4 vo;
        vo.x = va.x + bvv.x; vo.y = va.y + bvv.y;
        vo.z = va.z + bvv.z; vo.w = va.w + bvv.w;
        st4(Vbuf + row*DH + q*4, vo);
    }
}

// ---------------------------------------------------------------------------
// Kernel B1: partial KtV (16x16) + Ksum (16) per (batch, 64-row chunk)
// grid = B*CHUNKS = 512, block 256
// ---------------------------------------------------------------------------
__global__ __launch_bounds__(256) void reduce1(
    const float* __restrict__ Kbuf, const float* __restrict__ Vbuf,
    float* __restrict__ part)
{
    const int b  = blockIdx.x >> 6;
    const int ch = blockIdx.x & 63;
    const size_t base = ((size_t)b * N_ + (size_t)ch * RPC) * DH;

    __shared__ float sk[RPC][DH];
    __shared__ float sv[RPC][DH];
    const int t = threadIdx.x;
    st4(&sk[0][0] + t*4, ld4(Kbuf + base + t*4));   // 256 thr * f4 = 1024 floats
    st4(&sv[0][0] + t*4, ld4(Vbuf + base + t*4));
    __syncthreads();

    const int d = t >> 4, e = t & 15;
    float acc = 0.f;
    #pragma unroll 16
    for (int n = 0; n < RPC; ++n) acc += sk[n][d] * sv[n][e];
    float* p = part + (size_t)blockIdx.x * 272;
    p[t] = acc;

    if (t < DH) {
        float ss = 0.f;
        #pragma unroll 16
        for (int n = 0; n < RPC; ++n) ss += sk[n][t];
        p[256 + t] = ss;
    }
}

// ---------------------------------------------------------------------------
// Kernel B2: combine partials -> KtV[b][256], Ksum[b][16]
// ---------------------------------------------------------------------------
__global__ __launch_bounds__(320) void reduce2(
    const float* __restrict__ part,
    float* __restrict__ ktv, float* __restrict__ ksum)
{
    const int b = blockIdx.x;
    const int t = threadIdx.x;
    if (t < 272) {
        float s = 0.f;
        #pragma unroll
        for (int ch = 0; ch < CHUNKS; ++ch)
            s += part[((size_t)b*CHUNKS + ch) * 272 + t];
        if (t < 256) ktv[(size_t)b*256 + t] = s;
        else         ksum[(size_t)b*DH + (t - 256)] = s;
    }
}

// ---------------------------------------------------------------------------
// Kernel C: Q = elu1(x@Wq+bq); o = (Q@KtV)/(Q.Ksum+1e-6); out = o@Wo + bo
// lane: q = t&3 (4 head dims), s = (t>>2)&3 (K-slice of 1024 -> 256 each),
//       r = t>>4 (16 rows/block). grid = B*M/16 = 2048
// ---------------------------------------------------------------------------
__global__ __launch_bounds__(256) void out_kernel(
    const float* __restrict__ x,
    const float* __restrict__ Wq, const float* __restrict__ bq,
    const float* __restrict__ ktv, const float* __restrict__ ksum,
    const float* __restrict__ Wo, const float* __restrict__ bo,
    float* __restrict__ out)
{
    const int t = threadIdx.x;
    const int q = t & 3;
    const int s = (t >> 2) & 3;
    const int r = t >> 4;
    const size_t row = (size_t)blockIdx.x * 16 + r;
    const int b = (int)(row >> 12);
    const float* xrow = x + row * DM + s * (DM/4);

    // ---- Q partials: this lane: dims [4q,4q+4), k in [s*256, s*256+256) ----
    float4 qp = {0,0,0,0};
    #pragma unroll 4
    for (int ii = 0; ii < DM/16; ++ii) {       // 64 float4 chunks
        const float4 c = ld4(xrow + ii*4);
        const float cc[4] = {c.x, c.y, c.z, c.w};
        const int i0 = s*(DM/4) + ii*4;
        #pragma unroll
        for (int u = 0; u < 4; ++u) {
            const float4 w = ld4(Wq + (size_t)(i0+u)*DH + q*4);
            fma4(qp, cc[u], w);
        }
    }
    qp = add4(qp, sx4(qp, 4)); qp = add4(qp, sx4(qp, 8));

    const float4 bqv = ld4(bq + q*4);
    float4 qs;
    qs.x = elu1(qp.x + bqv.x); qs.y = elu1(qp.y + bqv.y);
    qs.z = elu1(qp.z + bqv.z); qs.w = elu1(qp.w + bqv.w);

    // gather the other 3 dim-groups (lanes differing in bits 0,1)
    const float4 qg1 = sx4(qs, 1);
    const float4 qg2 = sx4(qs, 2);
    const float4 qg3 = sx4(qs, 3);

    // ---- num (this lane's 4 out dims = [4q,4q+4)) and den ----
    const float* KT = ktv + (size_t)b*256;
    const float* KS = ksum + (size_t)b*DH;
    float den = 1e-6f;
    float4 num = {0,0,0,0};
    #define GRP(gexpr, R) { const int g = (gexpr); \
        const float4 k4 = ld4(KS + g*4); \
        den += R.x*k4.x + R.y*k4.y + R.z*k4.z + R.w*k4.w; \
        fma4(num, R.x, ld4(KT + (g*4+0)*16 + q*4)); \
        fma4(num, R.y, ld4(KT + (g*4+1)*16 + q*4)); \
        fma4(num, R.z, ld4(KT + (g*4+2)*16 + q*4)); \
        fma4(num, R.w, ld4(KT + (g*4+3)*16 + q*4)); }
    GRP(q,   qs)
    GRP(q^1, qg1)
    GRP(q^2, qg2)
    GRP(q^3, qg3)
    #undef GRP

    const float inv = 1.0f / den;
    float4 o; o.x = num.x*inv; o.y = num.y*inv; o.z = num.z*inv; o.w = num.w*inv;

    // gather all 16 o values (dim-groups q, q^1, q^2, q^3)
    const float4 ob = sx4(o, 1);
    const float4 oc = sx4(o, 2);
    const float4 od = sx4(o, 3);

    // ---- projection: 16 lanes per row cover 1024 cols, coalesced f4 ----
    const int lane16 = t & 15;
    float* orow = out + row * DM;
    #pragma unroll 2
    for (int j = 0; j < 16; ++j) {
        const int col = j*64 + lane16*4;
        float4 acc = ld4(bo + col);
        #define PRJ(gexpr, R) { const int g = (gexpr); \
            fma4(acc, R.x, ld4(Wo + (size_t)(g*4+0)*DM + col)); \
            fma4(acc, R.y, ld4(Wo + (size_t)(g*4+1)*DM + col)); \
            fma4(acc, R.z, ld4(Wo + (size_t)(g*4+2)*DM + col)); \
            fma4(acc, R.w, ld4(Wo + (size_t)(g*4+3)*DM + col)); }
        PRJ(q,   o)
        PRJ(q^1, ob)
        PRJ(q^2, oc)
        PRJ(q^3, od)
        #undef PRJ
        st4(orow + col, acc);
    }
}

// ---------------------------------------------------------------------------
extern "C" void kernel_launch(void* const* d_in, const int* in_sizes, int n_in,
                              void* d_out, int out_size, void* d_ws, size_t ws_size,
                              hipStream_t stream) {
    const float* x    = (const float*)d_in[0];
    const float* ctx  = (const float*)d_in[1];
    const float* Wq   = (const float*)d_in[2];
    const float* bq   = (const float*)d_in[3];
    const float* Wk   = (const float*)d_in[4];
    const float* bk   = (const float*)d_in[5];
    const float* Wv   = (const float*)d_in[6];
    const float* bv   = (const float*)d_in[7];
    const float* Wo   = (const float*)d_in[8];
    const float* bo   = (const float*)d_in[9];
    float* out = (float*)d_out;

    float* ws = (float*)d_ws;
    float* Kbuf = ws;                               // B*N*16 = 524288
    float* Vbuf = Kbuf + (size_t)B_*N_*DH;          // 524288
    float* part = Vbuf + (size_t)B_*N_*DH;          // B*CHUNKS*272 = 139264
    float* ktv  = part + (size_t)B_*CHUNKS*272;     // B*256
    float* ksum = ktv  + (size_t)B_*256;            // B*16

    kv_kernel<<<dim3(B_*N_/16), dim3(256), 0, stream>>>(ctx, Wk, bk, Wv, bv, Kbuf, Vbuf);
    reduce1<<<dim3(B_*CHUNKS), dim3(256), 0, stream>>>(Kbuf, Vbuf, part);
    reduce2<<<dim3(B_), dim3(320), 0, stream>>>(part, ktv, ksum);
    out_kernel<<<dim3(B_*M_/16), dim3(256), 0, stream>>>(x, Wq, bq, ktv, ksum, Wo, bo, out);
}

// Round 3
// 164.259 us; speedup vs baseline: 3.5552x; 2.4195x over previous
//
#include <hip/hip_runtime.h>
#include <math.h>

#define B_   8
#define M_   4096
#define N_   4096
#define DM   1024
#define DC   768
#define DH   16
#define CHUNKS 64
#define RPC (N_/CHUNKS)   // 64 rows per chunk
#define LDSTRIDE 132      // 128 + 4 pad (bank skew)

__device__ __forceinline__ float elu1(float t) {
    return t > 0.0f ? t + 1.0f : expf(t);
}
__device__ __forceinline__ float4 ld4(const float* p) { return *reinterpret_cast<const float4*>(p); }
__device__ __forceinline__ void  st4(float* p, float4 v) { *reinterpret_cast<float4*>(p) = v; }
__device__ __forceinline__ float4 sx4(float4 v, int m) {
    float4 r;
    r.x = __shfl_xor(v.x, m); r.y = __shfl_xor(v.y, m);
    r.z = __shfl_xor(v.z, m); r.w = __shfl_xor(v.w, m);
    return r;
}
__device__ __forceinline__ float4 add4(float4 a, float4 b) {
    float4 r; r.x=a.x+b.x; r.y=a.y+b.y; r.z=a.z+b.z; r.w=a.w+b.w; return r;
}
__device__ __forceinline__ void fma4(float4& a, float s, float4 w) {
    a.x = fmaf(s, w.x, a.x); a.y = fmaf(s, w.y, a.y);
    a.z = fmaf(s, w.z, a.z); a.w = fmaf(s, w.w, a.w);
}

// ---------------------------------------------------------------------------
// kv_kernel: K = elu1(ctx@Wk+bk), V = ctx@Wv+bv
// block 256 thr, 64 rows; thread: q=t&3 (head-dim f4), s=(t>>2)&3 (k-slot),
// g=t>>4 (rowgroup of 4). ctx staged in LDS per 128-col chunk (coalesced).
// grid = B*N/64 = 512
// ---------------------------------------------------------------------------
__global__ __launch_bounds__(256, 2) void kv_kernel(
    const float* __restrict__ ctx,
    const float* __restrict__ Wk, const float* __restrict__ bk,
    const float* __restrict__ Wv, const float* __restrict__ bv,
    float* __restrict__ Kbuf, float* __restrict__ Vbuf)
{
    __shared__ float xt[64 * LDSTRIDE];
    const int t = threadIdx.x;
    const int q = t & 3;
    const int s = (t >> 2) & 3;
    const int g = t >> 4;
    const size_t row0 = (size_t)blockIdx.x * 64;

    float4 ka[4], va[4];
    #pragma unroll
    for (int r = 0; r < 4; ++r) { ka[r] = make_float4(0,0,0,0); va[r] = make_float4(0,0,0,0); }

    for (int ch = 0; ch < DC/128; ++ch) {
        // stage 64 rows x 128 cols, coalesced (512B segments)
        #pragma unroll
        for (int i = 0; i < 8; ++i) {
            const int id = t + i*256;
            const int r  = id >> 5;
            const int c  = id & 31;
            st4(&xt[r*LDSTRIDE + c*4], ld4(ctx + (row0 + r)*DC + ch*128 + c*4));
        }
        __syncthreads();

        #pragma unroll
        for (int kk = 0; kk < 8; ++kk) {
            const int kl = kk*16 + s*4;          // lane's 4 k's (interleaved)
            const int kg = ch*128 + kl;          // global k
            const float4 wk0 = ld4(Wk + (size_t)(kg+0)*DH + q*4);
            const float4 wk1 = ld4(Wk + (size_t)(kg+1)*DH + q*4);
            const float4 wk2 = ld4(Wk + (size_t)(kg+2)*DH + q*4);
            const float4 wk3 = ld4(Wk + (size_t)(kg+3)*DH + q*4);
            const float4 wv0 = ld4(Wv + (size_t)(kg+0)*DH + q*4);
            const float4 wv1 = ld4(Wv + (size_t)(kg+1)*DH + q*4);
            const float4 wv2 = ld4(Wv + (size_t)(kg+2)*DH + q*4);
            const float4 wv3 = ld4(Wv + (size_t)(kg+3)*DH + q*4);
            #pragma unroll
            for (int r = 0; r < 4; ++r) {
                const float4 xv = ld4(&xt[(g*4 + r)*LDSTRIDE + kl]);
                fma4(ka[r], xv.x, wk0); fma4(ka[r], xv.y, wk1);
                fma4(ka[r], xv.z, wk2); fma4(ka[r], xv.w, wk3);
                fma4(va[r], xv.x, wv0); fma4(va[r], xv.y, wv1);
                fma4(va[r], xv.z, wv2); fma4(va[r], xv.w, wv3);
            }
        }
        __syncthreads();
    }

    // combine the 4 k-slots (lanes differing in bits 2,3)
    #pragma unroll
    for (int r = 0; r < 4; ++r) {
        ka[r] = add4(ka[r], sx4(ka[r], 4)); ka[r] = add4(ka[r], sx4(ka[r], 8));
        va[r] = add4(va[r], sx4(va[r], 4)); va[r] = add4(va[r], sx4(va[r], 8));
    }

    if (s == 0) {
        const float4 b4 = ld4(bk + q*4);
        #pragma unroll
        for (int r = 0; r < 4; ++r) {
            float4 o;
            o.x = elu1(ka[r].x + b4.x); o.y = elu1(ka[r].y + b4.y);
            o.z = elu1(ka[r].z + b4.z); o.w = elu1(ka[r].w + b4.w);
            st4(Kbuf + (row0 + g*4 + r)*DH + q*4, o);
        }
    } else if (s == 1) {
        const float4 b4 = ld4(bv + q*4);
        #pragma unroll
        for (int r = 0; r < 4; ++r) {
            float4 o;
            o.x = va[r].x + b4.x; o.y = va[r].y + b4.y;
            o.z = va[r].z + b4.z; o.w = va[r].w + b4.w;
            st4(Vbuf + (row0 + g*4 + r)*DH + q*4, o);
        }
    }
}

// ---------------------------------------------------------------------------
// reduce1: partial KtV (16x16) + Ksum (16) per 64-row chunk
// ---------------------------------------------------------------------------
__global__ __launch_bounds__(256) void reduce1(
    const float* __restrict__ Kbuf, const float* __restrict__ Vbuf,
    float* __restrict__ part)
{
    const size_t base = (size_t)blockIdx.x * RPC * DH;
    __shared__ float sk[RPC][DH];
    __shared__ float sv[RPC][DH];
    const int t = threadIdx.x;
    st4(&sk[0][0] + t*4, ld4(Kbuf + base + t*4));
    st4(&sv[0][0] + t*4, ld4(Vbuf + base + t*4));
    __syncthreads();

    const int d = t >> 4, e = t & 15;
    float acc = 0.f;
    #pragma unroll 16
    for (int n = 0; n < RPC; ++n) acc += sk[n][d] * sv[n][e];
    float* p = part + (size_t)blockIdx.x * 272;
    p[t] = acc;

    if (t < DH) {
        float ss = 0.f;
        #pragma unroll 16
        for (int n = 0; n < RPC; ++n) ss += sk[n][t];
        p[256 + t] = ss;
    }
}

// ---------------------------------------------------------------------------
// reduce2: combine partials -> comb[b][272] (256 KtV d-major + 16 Ksum)
// ---------------------------------------------------------------------------
__global__ __launch_bounds__(320) void reduce2(
    const float* __restrict__ part, float* __restrict__ comb)
{
    const int b = blockIdx.x;
    const int t = threadIdx.x;
    if (t < 272) {
        float s = 0.f;
        #pragma unroll
        for (int ch = 0; ch < CHUNKS; ++ch)
            s += part[((size_t)b*CHUNKS + ch) * 272 + t];
        comb[(size_t)b*272 + t] = s;
    }
}

// ---------------------------------------------------------------------------
// qo_kernel: Q = elu1(x@Wq+bq) (LDS only); o = (Q@KtV)/(Q.Ksum+1e-6);
//            out = o@Wo + bo  (Wo in registers, coalesced stores)
// block 256 thr, 64 rows; grid = B*M/64 = 512
// ---------------------------------------------------------------------------
__global__ __launch_bounds__(256, 2) void qo_kernel(
    const float* __restrict__ x,
    const float* __restrict__ Wq, const float* __restrict__ bq,
    const float* __restrict__ comb,
    const float* __restrict__ Wo, const float* __restrict__ bo,
    float* __restrict__ out)
{
    __shared__ float xt[64 * LDSTRIDE];
    __shared__ float qt[64 * DH];
    __shared__ float ot[64 * DH];
    __shared__ float kts[272];

    const int t = threadIdx.x;
    const int q = t & 3;
    const int s = (t >> 2) & 3;
    const int g = t >> 4;
    const size_t row0 = (size_t)blockIdx.x * 64;
    const int b = blockIdx.x >> 6;               // 64 blocks per batch

    float4 acc[4];
    #pragma unroll
    for (int r = 0; r < 4; ++r) acc[r] = make_float4(0,0,0,0);

    for (int ch = 0; ch < DM/128; ++ch) {
        #pragma unroll
        for (int i = 0; i < 8; ++i) {
            const int id = t + i*256;
            const int r  = id >> 5;
            const int c  = id & 31;
            st4(&xt[r*LDSTRIDE + c*4], ld4(x + (row0 + r)*DM + ch*128 + c*4));
        }
        __syncthreads();

        #pragma unroll
        for (int kk = 0; kk < 8; ++kk) {
            const int kl = kk*16 + s*4;
            const int kg = ch*128 + kl;
            const float4 w0 = ld4(Wq + (size_t)(kg+0)*DH + q*4);
            const float4 w1 = ld4(Wq + (size_t)(kg+1)*DH + q*4);
            const float4 w2 = ld4(Wq + (size_t)(kg+2)*DH + q*4);
            const float4 w3 = ld4(Wq + (size_t)(kg+3)*DH + q*4);
            #pragma unroll
            for (int r = 0; r < 4; ++r) {
                const float4 xv = ld4(&xt[(g*4 + r)*LDSTRIDE + kl]);
                fma4(acc[r], xv.x, w0); fma4(acc[r], xv.y, w1);
                fma4(acc[r], xv.z, w2); fma4(acc[r], xv.w, w3);
            }
        }
        __syncthreads();
    }

    #pragma unroll
    for (int r = 0; r < 4; ++r) {
        acc[r] = add4(acc[r], sx4(acc[r], 4));
        acc[r] = add4(acc[r], sx4(acc[r], 8));
    }

    if (s == 0) {
        const float4 b4 = ld4(bq + q*4);
        #pragma unroll
        for (int r = 0; r < 4; ++r) {
            float4 o;
            o.x = elu1(acc[r].x + b4.x); o.y = elu1(acc[r].y + b4.y);
            o.z = elu1(acc[r].z + b4.z); o.w = elu1(acc[r].w + b4.w);
            st4(&qt[(g*4 + r)*DH + q*4], o);
        }
    }
    if (t < 68) st4(&kts[t*4], ld4(comb + (size_t)b*272 + t*4));
    __syncthreads();

    // o per row: thread -> row r=t>>2, out-dims (t&3)*4..+4
    {
        const float* qrow = &qt[(t >> 2) * DH];
        const int jj = (t & 3) * 4;
        float den = 1e-6f;
        float4 num = make_float4(0,0,0,0);
        #pragma unroll
        for (int d4 = 0; d4 < 4; ++d4) {
            const float4 q4  = ld4(&qrow[d4*4]);
            const float4 ks4 = ld4(&kts[256 + d4*4]);
            den += q4.x*ks4.x + q4.y*ks4.y + q4.z*ks4.z + q4.w*ks4.w;
            fma4(num, q4.x, ld4(&kts[(d4*4+0)*DH + jj]));
            fma4(num, q4.y, ld4(&kts[(d4*4+1)*DH + jj]));
            fma4(num, q4.z, ld4(&kts[(d4*4+2)*DH + jj]));
            fma4(num, q4.w, ld4(&kts[(d4*4+3)*DH + jj]));
        }
        const float inv = 1.0f / den;
        float4 o4; o4.x = num.x*inv; o4.y = num.y*inv; o4.z = num.z*inv; o4.w = num.w*inv;
        st4(&ot[(t >> 2)*DH + jj], o4);
    }
    __syncthreads();

    // projection: thread owns cols 4t..4t+3 for all 64 rows; Wo in registers
    float4 wreg[16];
    #pragma unroll
    for (int e = 0; e < 16; ++e) wreg[e] = ld4(Wo + (size_t)e*DM + t*4);
    const float4 bov = ld4(bo + t*4);

    for (int r = 0; r < 64; ++r) {
        float4 a = bov;
        #pragma unroll
        for (int eo = 0; eo < 4; ++eo) {
            const float4 o4 = ld4(&ot[r*DH + eo*4]);
            fma4(a, o4.x, wreg[eo*4+0]); fma4(a, o4.y, wreg[eo*4+1]);
            fma4(a, o4.z, wreg[eo*4+2]); fma4(a, o4.w, wreg[eo*4+3]);
        }
        st4(out + (row0 + r)*DM + t*4, a);
    }
}

// ---------------------------------------------------------------------------
extern "C" void kernel_launch(void* const* d_in, const int* in_sizes, int n_in,
                              void* d_out, int out_size, void* d_ws, size_t ws_size,
                              hipStream_t stream) {
    const float* x    = (const float*)d_in[0];
    const float* ctx  = (const float*)d_in[1];
    const float* Wq   = (const float*)d_in[2];
    const float* bq   = (const float*)d_in[3];
    const float* Wk   = (const float*)d_in[4];
    const float* bk   = (const float*)d_in[5];
    const float* Wv   = (const float*)d_in[6];
    const float* bv   = (const float*)d_in[7];
    const float* Wo   = (const float*)d_in[8];
    const float* bo   = (const float*)d_in[9];
    float* out = (float*)d_out;

    float* ws = (float*)d_ws;
    float* Kbuf = ws;                               // B*N*16 = 524288
    float* Vbuf = Kbuf + (size_t)B_*N_*DH;          // 524288
    float* part = Vbuf + (size_t)B_*N_*DH;          // 512*272 = 139264
    float* comb = part + (size_t)B_*CHUNKS*272;     // 8*272

    kv_kernel<<<dim3(B_*N_/64), dim3(256), 0, stream>>>(ctx, Wk, bk, Wv, bv, Kbuf, Vbuf);
    reduce1<<<dim3(B_*CHUNKS), dim3(256), 0, stream>>>(Kbuf, Vbuf, part);
    reduce2<<<dim3(B_), dim3(320), 0, stream>>>(part, comb);
    qo_kernel<<<dim3(B_*M_/64), dim3(256), 0, stream>>>(x, Wq, bq, comb, Wo, bo, out);
}

// Round 4
// 150.556 us; speedup vs baseline: 3.8788x; 1.0910x over previous
//
#include <hip/hip_runtime.h>
#include <math.h>

#define B_   8
#define M_   4096
#define N_   4096
#define DM   1024
#define DC   768
#define DH   16
#define CHUNKS 64
#define RPC (N_/CHUNKS)   // 64 rows per chunk
#define LDSTRIDE 132      // 128 + 4 pad (bank skew)
#define QROWS 32

__device__ __forceinline__ float elu1(float t) {
    return t > 0.0f ? t + 1.0f : expf(t);
}
__device__ __forceinline__ float4 ld4(const float* p) { return *reinterpret_cast<const float4*>(p); }
__device__ __forceinline__ void  st4(float* p, float4 v) { *reinterpret_cast<float4*>(p) = v; }
__device__ __forceinline__ float4 sx4(float4 v, int m) {
    float4 r;
    r.x = __shfl_xor(v.x, m); r.y = __shfl_xor(v.y, m);
    r.z = __shfl_xor(v.z, m); r.w = __shfl_xor(v.w, m);
    return r;
}
__device__ __forceinline__ float4 add4(float4 a, float4 b) {
    float4 r; r.x=a.x+b.x; r.y=a.y+b.y; r.z=a.z+b.z; r.w=a.w+b.w; return r;
}
__device__ __forceinline__ void fma4(float4& a, float s, float4 w) {
    a.x = fmaf(s, w.x, a.x); a.y = fmaf(s, w.y, a.y);
    a.z = fmaf(s, w.z, a.z); a.w = fmaf(s, w.w, a.w);
}

// ---------------------------------------------------------------------------
// kv_kernel: K = elu1(ctx@Wk+bk), V = ctx@Wv+bv   (unchanged from round 3 —
// measured at/near BW floor)
// ---------------------------------------------------------------------------
__global__ __launch_bounds__(256, 2) void kv_kernel(
    const float* __restrict__ ctx,
    const float* __restrict__ Wk, const float* __restrict__ bk,
    const float* __restrict__ Wv, const float* __restrict__ bv,
    float* __restrict__ Kbuf, float* __restrict__ Vbuf)
{
    __shared__ float xt[64 * LDSTRIDE];
    const int t = threadIdx.x;
    const int q = t & 3;
    const int s = (t >> 2) & 3;
    const int g = t >> 4;
    const size_t row0 = (size_t)blockIdx.x * 64;

    float4 ka[4], va[4];
    #pragma unroll
    for (int r = 0; r < 4; ++r) { ka[r] = make_float4(0,0,0,0); va[r] = make_float4(0,0,0,0); }

    for (int ch = 0; ch < DC/128; ++ch) {
        #pragma unroll
        for (int i = 0; i < 8; ++i) {
            const int id = t + i*256;
            const int r  = id >> 5;
            const int c  = id & 31;
            st4(&xt[r*LDSTRIDE + c*4], ld4(ctx + (row0 + r)*DC + ch*128 + c*4));
        }
        __syncthreads();

        #pragma unroll
        for (int kk = 0; kk < 8; ++kk) {
            const int kl = kk*16 + s*4;
            const int kg = ch*128 + kl;
            const float4 wk0 = ld4(Wk + (size_t)(kg+0)*DH + q*4);
            const float4 wk1 = ld4(Wk + (size_t)(kg+1)*DH + q*4);
            const float4 wk2 = ld4(Wk + (size_t)(kg+2)*DH + q*4);
            const float4 wk3 = ld4(Wk + (size_t)(kg+3)*DH + q*4);
            const float4 wv0 = ld4(Wv + (size_t)(kg+0)*DH + q*4);
            const float4 wv1 = ld4(Wv + (size_t)(kg+1)*DH + q*4);
            const float4 wv2 = ld4(Wv + (size_t)(kg+2)*DH + q*4);
            const float4 wv3 = ld4(Wv + (size_t)(kg+3)*DH + q*4);
            #pragma unroll
            for (int r = 0; r < 4; ++r) {
                const float4 xv = ld4(&xt[(g*4 + r)*LDSTRIDE + kl]);
                fma4(ka[r], xv.x, wk0); fma4(ka[r], xv.y, wk1);
                fma4(ka[r], xv.z, wk2); fma4(ka[r], xv.w, wk3);
                fma4(va[r], xv.x, wv0); fma4(va[r], xv.y, wv1);
                fma4(va[r], xv.z, wv2); fma4(va[r], xv.w, wv3);
            }
        }
        __syncthreads();
    }

    #pragma unroll
    for (int r = 0; r < 4; ++r) {
        ka[r] = add4(ka[r], sx4(ka[r], 4)); ka[r] = add4(ka[r], sx4(ka[r], 8));
        va[r] = add4(va[r], sx4(va[r], 4)); va[r] = add4(va[r], sx4(va[r], 8));
    }

    if (s == 0) {
        const float4 b4 = ld4(bk + q*4);
        #pragma unroll
        for (int r = 0; r < 4; ++r) {
            float4 o;
            o.x = elu1(ka[r].x + b4.x); o.y = elu1(ka[r].y + b4.y);
            o.z = elu1(ka[r].z + b4.z); o.w = elu1(ka[r].w + b4.w);
            st4(Kbuf + (row0 + g*4 + r)*DH + q*4, o);
        }
    } else if (s == 1) {
        const float4 b4 = ld4(bv + q*4);
        #pragma unroll
        for (int r = 0; r < 4; ++r) {
            float4 o;
            o.x = va[r].x + b4.x; o.y = va[r].y + b4.y;
            o.z = va[r].z + b4.z; o.w = va[r].w + b4.w;
            st4(Vbuf + (row0 + g*4 + r)*DH + q*4, o);
        }
    }
}

// ---------------------------------------------------------------------------
// reduce1: partial KtV (16x16) + Ksum (16) per 64-row chunk
// ---------------------------------------------------------------------------
__global__ __launch_bounds__(256) void reduce1(
    const float* __restrict__ Kbuf, const float* __restrict__ Vbuf,
    float* __restrict__ part)
{
    const size_t base = (size_t)blockIdx.x * RPC * DH;
    __shared__ float sk[RPC][DH];
    __shared__ float sv[RPC][DH];
    const int t = threadIdx.x;
    st4(&sk[0][0] + t*4, ld4(Kbuf + base + t*4));
    st4(&sv[0][0] + t*4, ld4(Vbuf + base + t*4));
    __syncthreads();

    const int d = t >> 4, e = t & 15;
    float acc = 0.f;
    #pragma unroll 16
    for (int n = 0; n < RPC; ++n) acc += sk[n][d] * sv[n][e];
    float* p = part + (size_t)blockIdx.x * 272;
    p[t] = acc;

    if (t < DH) {
        float ss = 0.f;
        #pragma unroll 16
        for (int n = 0; n < RPC; ++n) ss += sk[n][t];
        p[256 + t] = ss;
    }
}

// ---------------------------------------------------------------------------
// reduce2: combine partials -> comb[b][272] (256 KtV d-major + 16 Ksum)
// ---------------------------------------------------------------------------
__global__ __launch_bounds__(320) void reduce2(
    const float* __restrict__ part, float* __restrict__ comb)
{
    const int b = blockIdx.x;
    const int t = threadIdx.x;
    if (t < 272) {
        float s = 0.f;
        #pragma unroll
        for (int ch = 0; ch < CHUNKS; ++ch)
            s += part[((size_t)b*CHUNKS + ch) * 272 + t];
        comb[(size_t)b*272 + t] = s;
    }
}

// ---------------------------------------------------------------------------
// qo_kernel v3: 32 rows/block (grid 1024 = 4 blocks/CU), double-buffered LDS
// staging with early global-load issue, 1 sync per chunk.
// ---------------------------------------------------------------------------
__global__ __launch_bounds__(256) void qo_kernel(
    const float* __restrict__ x,
    const float* __restrict__ Wq, const float* __restrict__ bq,
    const float* __restrict__ comb,
    const float* __restrict__ Wo, const float* __restrict__ bo,
    float* __restrict__ out)
{
    __shared__ float xt[2][QROWS * LDSTRIDE];
    __shared__ float qt[QROWS * DH];
    __shared__ float ot[QROWS * DH];
    __shared__ float kts[272];

    const int t = threadIdx.x;
    const int q = t & 3;
    const int s = (t >> 2) & 3;
    const int g = t >> 4;                    // 0..15, owns rows g*2, g*2+1
    const size_t row0 = (size_t)blockIdx.x * QROWS;
    const int b = blockIdx.x >> 7;           // 128 blocks per batch
    const float* xbase = x + row0 * DM;

    const int rbase = t >> 5;                // staging row base (0..7)
    const int c4    = (t & 31) * 4;          // staging col (floats)

    float4 acc[2];
    acc[0] = make_float4(0,0,0,0); acc[1] = make_float4(0,0,0,0);
    float4 A[4], Bf[4];

#define SLOAD(ch, buf) { \
    _Pragma("unroll") for (int i = 0; i < 4; ++i) \
        buf[i] = ld4(xbase + (size_t)(rbase + i*8)*DM + (ch)*128 + c4); }
#define SWRITE(pb, buf) { \
    _Pragma("unroll") for (int i = 0; i < 4; ++i) \
        st4(&xt[pb][(rbase + i*8)*LDSTRIDE + c4], buf[i]); }
#define COMPUTE(ch, pb) { \
    _Pragma("unroll") for (int kk = 0; kk < 8; ++kk) { \
        const int kl = kk*16 + s*4; \
        const int kg = (ch)*128 + kl; \
        const float4 w0 = ld4(Wq + (size_t)(kg+0)*DH + q*4); \
        const float4 w1 = ld4(Wq + (size_t)(kg+1)*DH + q*4); \
        const float4 w2 = ld4(Wq + (size_t)(kg+2)*DH + q*4); \
        const float4 w3 = ld4(Wq + (size_t)(kg+3)*DH + q*4); \
        _Pragma("unroll") for (int r = 0; r < 2; ++r) { \
            const float4 xv = ld4(&xt[pb][(g*2 + r)*LDSTRIDE + kl]); \
            fma4(acc[r], xv.x, w0); fma4(acc[r], xv.y, w1); \
            fma4(acc[r], xv.z, w2); fma4(acc[r], xv.w, w3); } } }

    SLOAD(0, A);
    SWRITE(0, A);
    #pragma unroll
    for (int cc = 0; cc < 4; ++cc) {
        const int ch = cc*2;
        __syncthreads();
        if (ch < 7) SLOAD(ch+1, Bf);     // issue next-chunk loads early
        COMPUTE(ch, 0);
        if (ch < 7) SWRITE(1, Bf);       // land them after compute
        __syncthreads();
        if (ch+1 < 7) SLOAD(ch+2, A);
        COMPUTE(ch+1, 1);
        if (ch+1 < 7) SWRITE(0, A);
    }
#undef SLOAD
#undef SWRITE
#undef COMPUTE

    // combine the 4 k-slots (lanes differing in bits 2,3)
    #pragma unroll
    for (int r = 0; r < 2; ++r) {
        acc[r] = add4(acc[r], sx4(acc[r], 4));
        acc[r] = add4(acc[r], sx4(acc[r], 8));
    }

    if (s == 0) {
        const float4 b4 = ld4(bq + q*4);
        #pragma unroll
        for (int r = 0; r < 2; ++r) {
            float4 o;
            o.x = elu1(acc[r].x + b4.x); o.y = elu1(acc[r].y + b4.y);
            o.z = elu1(acc[r].z + b4.z); o.w = elu1(acc[r].w + b4.w);
            st4(&qt[(g*2 + r)*DH + q*4], o);
        }
    }
    if (t < 68) st4(&kts[t*4], ld4(comb + (size_t)b*272 + t*4));
    __syncthreads();

    // o per row: threads 0..127 -> row r=t>>2, out-dims (t&3)*4..+4
    if (t < 128) {
        const float* qrow = &qt[(t >> 2) * DH];
        const int jj = (t & 3) * 4;
        float den = 1e-6f;
        float4 num = make_float4(0,0,0,0);
        #pragma unroll
        for (int d4 = 0; d4 < 4; ++d4) {
            const float4 q4  = ld4(&qrow[d4*4]);
            const float4 ks4 = ld4(&kts[256 + d4*4]);
            den += q4.x*ks4.x + q4.y*ks4.y + q4.z*ks4.z + q4.w*ks4.w;
            fma4(num, q4.x, ld4(&kts[(d4*4+0)*DH + jj]));
            fma4(num, q4.y, ld4(&kts[(d4*4+1)*DH + jj]));
            fma4(num, q4.z, ld4(&kts[(d4*4+2)*DH + jj]));
            fma4(num, q4.w, ld4(&kts[(d4*4+3)*DH + jj]));
        }
        const float inv = 1.0f / den;
        float4 o4; o4.x = num.x*inv; o4.y = num.y*inv; o4.z = num.z*inv; o4.w = num.w*inv;
        st4(&ot[(t >> 2)*DH + jj], o4);
    }
    __syncthreads();

    // projection: thread owns cols 4t..4t+3 for all 32 rows; Wo in registers
    float4 wreg[16];
    #pragma unroll
    for (int e = 0; e < 16; ++e) wreg[e] = ld4(Wo + (size_t)e*DM + t*4);
    const float4 bov = ld4(bo + t*4);

    for (int r = 0; r < QROWS; ++r) {
        float4 a = bov;
        #pragma unroll
        for (int eo = 0; eo < 4; ++eo) {
            const float4 o4 = ld4(&ot[r*DH + eo*4]);
            fma4(a, o4.x, wreg[eo*4+0]); fma4(a, o4.y, wreg[eo*4+1]);
            fma4(a, o4.z, wreg[eo*4+2]); fma4(a, o4.w, wreg[eo*4+3]);
        }
        st4(out + (row0 + r)*DM + t*4, a);
    }
}

// ---------------------------------------------------------------------------
extern "C" void kernel_launch(void* const* d_in, const int* in_sizes, int n_in,
                              void* d_out, int out_size, void* d_ws, size_t ws_size,
                              hipStream_t stream) {
    const float* x    = (const float*)d_in[0];
    const float* ctx  = (const float*)d_in[1];
    const float* Wq   = (const float*)d_in[2];
    const float* bq   = (const float*)d_in[3];
    const float* Wk   = (const float*)d_in[4];
    const float* bk   = (const float*)d_in[5];
    const float* Wv   = (const float*)d_in[6];
    const float* bv   = (const float*)d_in[7];
    const float* Wo   = (const float*)d_in[8];
    const float* bo   = (const float*)d_in[9];
    float* out = (float*)d_out;

    float* ws = (float*)d_ws;
    float* Kbuf = ws;                               // B*N*16 = 524288
    float* Vbuf = Kbuf + (size_t)B_*N_*DH;          // 524288
    float* part = Vbuf + (size_t)B_*N_*DH;          // 512*272 = 139264
    float* comb = part + (size_t)B_*CHUNKS*272;     // 8*272

    kv_kernel<<<dim3(B_*N_/64), dim3(256), 0, stream>>>(ctx, Wk, bk, Wv, bv, Kbuf, Vbuf);
    reduce1<<<dim3(B_*CHUNKS), dim3(256), 0, stream>>>(Kbuf, Vbuf, part);
    reduce2<<<dim3(B_), dim3(320), 0, stream>>>(part, comb);
    qo_kernel<<<dim3(B_*M_/32), dim3(256), 0, stream>>>(x, Wq, bq, comb, Wo, bo, out);
}